// Round 5
// baseline (2321.085 us; speedup 1.0000x reference)
//
#include <hip/hip_runtime.h>
#include <hip/hip_bf16.h>
#include <hip/hip_fp16.h>
#include <cstdint>
#include <cstddef>

// ---------------------------------------------------------------------------
// Types
// ---------------------------------------------------------------------------
typedef _Float16 half8 __attribute__((ext_vector_type(8)));
typedef float float4v __attribute__((ext_vector_type(4)));
typedef unsigned int uint4v __attribute__((ext_vector_type(4)));

#define GLOBAL_AS(p) ((__attribute__((address_space(1))) void*)(p))
#define LDS_AS(p) ((__attribute__((address_space(3))) void*)(p))

// async global->LDS, 16B per lane, dest = base + lane*16 (wave-uniform base)
__device__ __forceinline__ void gll16(const void* g, void* l) {
  __builtin_amdgcn_global_load_lds(GLOBAL_AS(g), LDS_AS(l), 16, 0, 0);
}

// write-through store (sc0 sc1: visible at coherence point) -- h/publ data
// exchanged across blocks within the scan kernel.
__device__ __forceinline__ void store_h_cc(_Float16* addr, _Float16 v) {
  unsigned short u = __builtin_bit_cast(unsigned short, v);
  asm volatile("global_store_short %0, %1, off sc0 sc1" ::"v"(addr), "v"(u) : "memory");
}

// 8x coherent 16B loads from one base (+128B strides), single vmcnt drain.
// sc0 sc1 bypass L1/L2 so no acquire fence (buffer_inv) is needed to observe
// other blocks' write-through stores.
__device__ __forceinline__ void stage8_cc(const _Float16* base, uint4v& d0, uint4v& d1,
                                          uint4v& d2, uint4v& d3, uint4v& d4, uint4v& d5,
                                          uint4v& d6, uint4v& d7) {
  asm volatile(
      "global_load_dwordx4 %0, %8, off sc0 sc1\n\t"
      "global_load_dwordx4 %1, %8, off offset:128 sc0 sc1\n\t"
      "global_load_dwordx4 %2, %8, off offset:256 sc0 sc1\n\t"
      "global_load_dwordx4 %3, %8, off offset:384 sc0 sc1\n\t"
      "global_load_dwordx4 %4, %8, off offset:512 sc0 sc1\n\t"
      "global_load_dwordx4 %5, %8, off offset:640 sc0 sc1\n\t"
      "global_load_dwordx4 %6, %8, off offset:768 sc0 sc1\n\t"
      "global_load_dwordx4 %7, %8, off offset:896 sc0 sc1\n\t"
      "s_waitcnt vmcnt(0)"
      : "=&v"(d0), "=&v"(d1), "=&v"(d2), "=&v"(d3), "=&v"(d4), "=&v"(d5), "=&v"(d6), "=&v"(d7)
      : "v"(base)
      : "memory");
}

__device__ __forceinline__ float sigm(float x) { return 1.f / (1.f + __expf(-x)); }
__device__ __forceinline__ float tanh_fast(float x) { return 2.f / (1.f + __expf(-2.f * x)) - 1.f; }

// ---------------------------------------------------------------------------
// Weight transpose + fp32->fp16 convert.  W: K x N (row-major) -> WT: N x K.
// perm=1: output row n' = 4*(n&511) + (n>>9)   (gate interleave for Wi/Wh)
// ---------------------------------------------------------------------------
__global__ void transpose_cvt(const float* __restrict__ W, _Float16* __restrict__ WT,
                              int K, int N, int perm) {
  __shared__ float tile[32][33];
  int n0 = blockIdx.x * 32, k0 = blockIdx.y * 32;
  int tx = threadIdx.x, ty = threadIdx.y;  // (32, 8)
#pragma unroll
  for (int i = 0; i < 32; i += 8)
    tile[ty + i][tx] = W[(size_t)(k0 + ty + i) * N + n0 + tx];
  __syncthreads();
#pragma unroll
  for (int i = 0; i < 32; i += 8) {
    int n = n0 + ty + i;
    int nr = perm ? ((n & 511) * 4 + (n >> 9)) : n;
    WT[(size_t)nr * K + k0 + tx] = (_Float16)tile[tx][ty + i];
  }
}

// ---------------------------------------------------------------------------
// Build WqT (32 x 512): rows 0..20 = Wa[:,n] + Wv[:,0], rows 21..31 zero.
// bq[n] = ba[n] + bv.  bperm = gate-interleaved b_lstm.
// ---------------------------------------------------------------------------
__global__ void prep_small(const float* __restrict__ Wv, const float* __restrict__ bv,
                           const float* __restrict__ Wa, const float* __restrict__ ba,
                           const float* __restrict__ b_lstm, _Float16* __restrict__ WqT,
                           float* __restrict__ bq, float* __restrict__ bperm) {
  int idx = blockIdx.x * 256 + threadIdx.x;
  if (idx < 16384) {
    int n = idx >> 9, k = idx & 511;
    float v = (n < 21) ? (Wa[k * 21 + n] + Wv[k]) : 0.f;
    WqT[idx] = (_Float16)v;
  }
  if (idx < 2048) bperm[idx] = b_lstm[(idx & 3) * 512 + (idx >> 2)];
  if (idx < 32) bq[idx] = (idx < 21) ? (ba[idx] + bv[0]) : 0.f;
}

// ---------------------------------------------------------------------------
// obs (T*B x 1024 fp32) -> priv_s (T*B x 512 fp16), publ_s (T*B x 512 fp16)
// ---------------------------------------------------------------------------
__global__ void convert_obs(const float* __restrict__ obs, _Float16* __restrict__ priv_s,
                            _Float16* __restrict__ publ_s) {
  size_t id = (size_t)blockIdx.x * blockDim.x + threadIdx.x;  // T*B*128 threads
  size_t tb = id >> 7;
  int c8 = (int)(id & 127);
  const float4* src = (const float4*)(obs + tb * 1024 + (size_t)c8 * 8);
  float4 v0 = src[0], v1 = src[1];
  half8 h;
  h[0] = (_Float16)v0.x; h[1] = (_Float16)v0.y; h[2] = (_Float16)v0.z; h[3] = (_Float16)v0.w;
  h[4] = (_Float16)v1.x; h[5] = (_Float16)v1.y; h[6] = (_Float16)v1.z; h[7] = (_Float16)v1.w;
  _Float16* dst = (c8 < 64) ? (priv_s + tb * 512 + (size_t)c8 * 8)
                            : (publ_s + tb * 512 + (size_t)(c8 - 64) * 8);
  *(half8*)dst = h;
}

// ---------------------------------------------------------------------------
// init scan state: hb0 = h0 (fp16), unmasked (mask applied at staging time).
// Also zero barrier state.
// ---------------------------------------------------------------------------
__global__ void init_scan(const float* __restrict__ h0, _Float16* __restrict__ hbuf,
                          int* __restrict__ bar) {
  int idx = blockIdx.x * 256 + threadIdx.x;  // 131072
  hbuf[idx] = (_Float16)h0[idx];
  if (idx < 256) bar[idx] = 0;
}

// ---------------------------------------------------------------------------
// Generic fp16 GEMM: C = A(MxK) @ Bt(NxK)^T, fp32 acc, +bias [, relu] -> fp16
// 128x128 tile, 4 waves of 64x64, BK=32, global_load_lds staging.
// SW=1: m-major grid (x = row-tile) so n-siblings of a row-band share an XCD
// under id%8 round-robin -> A re-reads hit L2.
// ---------------------------------------------------------------------------
template <int RELU, int SW>
__global__ __launch_bounds__(256) void gemm_f16(const _Float16* __restrict__ A,
                                                const _Float16* __restrict__ Bt,
                                                const float* __restrict__ bias,
                                                _Float16* __restrict__ out, int M, int N, int K) {
  __shared__ __align__(16) _Float16 Ash[4096];
  __shared__ __align__(16) _Float16 Bsh[4096];
  const int tid = threadIdx.x;
  const int w = tid >> 6, lane = tid & 63;
  const int quad = lane >> 4, fid = lane & 15;
  const int nT = (SW ? blockIdx.y : blockIdx.x) * 128;
  const int mT = (SW ? blockIdx.x : blockIdx.y) * 128;
  const int wm = (w & 1) * 64, wn = (w >> 1) * 64;
  float4v acc[4][4] = {};

  const int slot0 = (w * 2) * 64 + lane;
  const int slot1 = (w * 2 + 1) * 64 + lane;
  const int m0 = slot0 & 127, q0 = slot0 >> 7;
  const int m1 = slot1 & 127, q1 = slot1 >> 7;

  for (int k0 = 0; k0 < K; k0 += 32) {
    __syncthreads();
    gll16(A + (size_t)(mT + m0) * K + k0 + q0 * 8, &Ash[(size_t)(w * 2) * 64 * 8]);
    gll16(A + (size_t)(mT + m1) * K + k0 + q1 * 8, &Ash[(size_t)(w * 2 + 1) * 64 * 8]);
    gll16(Bt + (size_t)(nT + m0) * K + k0 + q0 * 8, &Bsh[(size_t)(w * 2) * 64 * 8]);
    gll16(Bt + (size_t)(nT + m1) * K + k0 + q1 * 8, &Bsh[(size_t)(w * 2 + 1) * 64 * 8]);
    __syncthreads();
    half8 af[4], bf[4];
#pragma unroll
    for (int i = 0; i < 4; i++)
      af[i] = *(const half8*)&Ash[(size_t)(quad * 128 + wm + i * 16 + fid) * 8];
#pragma unroll
    for (int i = 0; i < 4; i++)
      bf[i] = *(const half8*)&Bsh[(size_t)(quad * 128 + wn + i * 16 + fid) * 8];
#pragma unroll
    for (int mi = 0; mi < 4; mi++)
#pragma unroll
      for (int ni = 0; ni < 4; ni++)
        acc[mi][ni] = __builtin_amdgcn_mfma_f32_16x16x32_f16(af[mi], bf[ni], acc[mi][ni], 0, 0, 0);
  }
#pragma unroll
  for (int mi = 0; mi < 4; mi++) {
#pragma unroll
    for (int ni = 0; ni < 4; ni++) {
      int col = nT + wn + ni * 16 + fid;
      float bb = bias[col];
#pragma unroll
      for (int r = 0; r < 4; r++) {
        int row = mT + wm + mi * 16 + quad * 4 + r;
        float v = acc[mi][ni][r] + bb;
        if (RELU) v = fmaxf(v, 0.f);
        out[(size_t)row * N + col] = (_Float16)v;
      }
    }
  }
}

// ---------------------------------------------------------------------------
// Persistent LSTM scan.  1-D grid of 128 blocks, 256 threads.
// grp = bid & 7 (m-group), bx = bid >> 3 (n-tile).  Tile: 32 rows x 128 cols.
// Wh and c-state register-resident.  h exchange: publ (write-through sc0 sc1
// stores), staged next step via sc0 sc1 loads (L1/L2 bypass) with the dones
// mask applied at staging time -- NO hnext buffer, NO acquire fence ever.
// Barrier: per-m-group monotonic counter, relaxed atomics only.
// ---------------------------------------------------------------------------
__global__ __launch_bounds__(256, 1) void lstm_scan(
    const _Float16* __restrict__ WhT, const _Float16* __restrict__ xg,
    const float* __restrict__ c0, const int* __restrict__ dones,
    const _Float16* __restrict__ hb0, _Float16* __restrict__ publ,
    float* __restrict__ outc, float* __restrict__ outh, int* __restrict__ bar) {
  __shared__ __align__(16) _Float16 Ash[16384];  // 32 rows x 512 k

  const int tid = threadIdx.x;
  const int w = tid >> 6, lane = tid & 63;
  const int quad = lane >> 4, fid = lane & 15;
  const int bid = blockIdx.x;
  const int grp = bid & 7;          // m-group
  const int nT = (bid >> 3) * 128;  // gate-col tile
  const int m0 = grp * 32;          // batch-row tile
  const int wn = w * 32;            // wave's 32 gate-cols within tile
  int* cnt = bar + grp * 32;        // 128B-separated per-group counters

  const int srow = tid & 31;  // staging row (this thread's 8 slots share it)
  const int scol = tid >> 5;  // 0..7: first k-chunk index

  // ---- load Wh fragments into registers (one-time) ----
  half8 bfr[16][2];
#pragma unroll
  for (int kc = 0; kc < 16; kc++)
#pragma unroll
    for (int ni = 0; ni < 2; ni++)
      bfr[kc][ni] = *(const half8*)&WhT[(size_t)(nT + wn + ni * 16 + fid) * 512 + kc * 32 + quad * 8];

  // ---- init c-state registers (lane3==0 lanes own values) ----
  const int lane3 = lane & 3;
  const int base = lane & ~3;
  float cc[2][2][4];
#pragma unroll
  for (int mi = 0; mi < 2; mi++)
#pragma unroll
    for (int ni = 0; ni < 2; ni++) {
      int col = nT + wn + ni * 16 + fid;
      int j = col >> 2;
#pragma unroll
      for (int r = 0; r < 4; r++) {
        int row = m0 + mi * 16 + quad * 4 + r;
        float cv = 0.f;
        if (lane3 == 0) cv = dones[row] ? 0.f : c0[(size_t)row * 512 + j];
        cc[mi][ni][r] = cv;
      }
    }

  // ---- prefetch xg for t=0 ----
  _Float16 xgv[2][2][4];
#pragma unroll
  for (int mi = 0; mi < 2; mi++)
#pragma unroll
    for (int ni = 0; ni < 2; ni++) {
      int col = nT + wn + ni * 16 + fid;
#pragma unroll
      for (int r = 0; r < 4; r++)
        xgv[mi][ni][r] = xg[(size_t)(m0 + mi * 16 + quad * 4 + r) * 2048 + col];
    }

  for (int t = 0; t < 128; t++) {
    // ---- stage h_{t} source tile into LDS (coherent loads, mask dones[t]) --
    const _Float16* hsrc = (t == 0) ? (hb0 + (size_t)(m0 + srow) * 512)
                                    : (publ + ((size_t)(t - 1) * 256 + m0 + srow) * 512);
    uint4v d0, d1, d2, d3, d4, d5, d6, d7;
    stage8_cc(hsrc + scol * 8, d0, d1, d2, d3, d4, d5, d6, d7);
    if (dones[t * 256 + m0 + srow]) {
      uint4v z = {0u, 0u, 0u, 0u};
      d0 = z; d1 = z; d2 = z; d3 = z; d4 = z; d5 = z; d6 = z; d7 = z;
    }
    {
      uint4v* lds = (uint4v*)Ash;
      lds[tid] = d0;
      lds[tid + 256] = d1;
      lds[tid + 512] = d2;
      lds[tid + 768] = d3;
      lds[tid + 1024] = d4;
      lds[tid + 1280] = d5;
      lds[tid + 1536] = d6;
      lds[tid + 1792] = d7;
    }
    __syncthreads();

    // ---- K-loop: 16 chunks of 32; per chunk 2 a-frags, 2x2 MFMA ----
    float4v acc[2][2] = {};
#pragma unroll
    for (int kc = 0; kc < 16; kc++) {
      half8 af[2];
#pragma unroll
      for (int mi = 0; mi < 2; mi++)
        af[mi] = *(const half8*)&Ash[(size_t)((kc * 4 + quad) * 32 + mi * 16 + fid) * 8];
#pragma unroll
      for (int mi = 0; mi < 2; mi++)
#pragma unroll
        for (int ni = 0; ni < 2; ni++)
          acc[mi][ni] = __builtin_amdgcn_mfma_f32_16x16x32_f16(af[mi], bfr[kc][ni], acc[mi][ni], 0, 0, 0);
    }

    // ---- epilogue: gates -> c,h; store h (write-through) to publ ----
    const int tn = (t < 127) ? (t + 1) : 127;
#pragma unroll
    for (int mi = 0; mi < 2; mi++) {
#pragma unroll
      for (int ni = 0; ni < 2; ni++) {
        int col = nT + wn + ni * 16 + fid;
        int j = col >> 2;
#pragma unroll
        for (int r = 0; r < 4; r++) {
          int row = m0 + mi * 16 + quad * 4 + r;
          float gate = acc[mi][ni][r] + (float)xgv[mi][ni][r];
          float gi = __shfl(gate, base + 0, 64);
          float gf = __shfl(gate, base + 1, 64);
          float gg = __shfl(gate, base + 2, 64);
          float go = __shfl(gate, base + 3, 64);
          if (lane3 == 0) {
            float i_ = sigm(gi), f_ = sigm(gf), o_ = sigm(go);
            float g_ = tanh_fast(gg);
            float c_new = f_ * cc[mi][ni][r] + i_ * g_;
            float h_new = o_ * tanh_fast(c_new);
            store_h_cc(publ + ((size_t)t * 256 + row) * 512 + j, (_Float16)h_new);
            if (t < 127) {
              cc[mi][ni][r] = dones[(size_t)tn * 256 + row] ? 0.f : c_new;
            } else {
              outc[(size_t)row * 512 + j] = c_new;
              outh[(size_t)row * 512 + j] = h_new;
            }
          }
        }
      }
    }

    if (t < 127) {
      // prefetch xg for t+1 BEFORE the barrier (overlaps with store drain)
#pragma unroll
      for (int mi = 0; mi < 2; mi++)
#pragma unroll
        for (int ni = 0; ni < 2; ni++) {
          int col = nT + wn + ni * 16 + fid;
#pragma unroll
          for (int r = 0; r < 4; r++)
            xgv[mi][ni][r] =
                xg[((size_t)(t + 1) * 256 + m0 + mi * 16 + quad * 4 + r) * 2048 + col];
        }

      // drain stores (and xg loads) then per-m-group monotonic barrier;
      // relaxed atomics only -- no fence (staging loads bypass caches).
      __syncthreads();
      if (tid == 0) {
        int target = 16 * (t + 1);
        int seen = __hip_atomic_fetch_add(cnt, 1, __ATOMIC_RELAXED, __HIP_MEMORY_SCOPE_AGENT) + 1;
        while (seen < target) {
          __builtin_amdgcn_s_sleep(1);
          seen = __hip_atomic_load(cnt, __ATOMIC_RELAXED, __HIP_MEMORY_SCOPE_AGENT);
        }
      }
      __syncthreads();
    }
  }
}

// ---------------------------------------------------------------------------
// final: q = (p3 .* publ) @ WqT^T + bq  -> out (T*B x 21) fp32
// ---------------------------------------------------------------------------
__global__ __launch_bounds__(256) void final_q(const _Float16* __restrict__ p3,
                                               const _Float16* __restrict__ publ,
                                               const _Float16* __restrict__ WqT,
                                               const float* __restrict__ bq,
                                               float* __restrict__ outq) {
  int tid = threadIdx.x, w = tid >> 6, lane = tid & 63;
  int quad = lane >> 4, fid = lane & 15;
  size_t r0 = ((size_t)blockIdx.x * 4 + w) * 16;
  float4v acc0 = {}, acc1 = {};
#pragma unroll
  for (int kk = 0; kk < 512; kk += 32) {
    half8 a = *(const half8*)(p3 + (r0 + fid) * 512 + kk + quad * 8);
    half8 b = *(const half8*)(publ + (r0 + fid) * 512 + kk + quad * 8);
    half8 af;
#pragma unroll
    for (int j = 0; j < 8; j++) af[j] = (_Float16)((float)a[j] * (float)b[j]);
    half8 b0 = *(const half8*)&WqT[(size_t)fid * 512 + kk + quad * 8];
    half8 b1 = *(const half8*)&WqT[(size_t)(16 + fid) * 512 + kk + quad * 8];
    acc0 = __builtin_amdgcn_mfma_f32_16x16x32_f16(af, b0, acc0, 0, 0, 0);
    acc1 = __builtin_amdgcn_mfma_f32_16x16x32_f16(af, b1, acc1, 0, 0, 0);
  }
#pragma unroll
  for (int r = 0; r < 4; r++) {
    size_t row = r0 + quad * 4 + r;
    int c0 = fid, c1 = 16 + fid;
    outq[row * 21 + c0] = acc0[r] + bq[c0];
    if (c1 < 21) outq[row * 21 + c1] = acc1[r] + bq[c1];
  }
}

// ---------------------------------------------------------------------------
// launcher
// ---------------------------------------------------------------------------
extern "C" void kernel_launch(void* const* d_in, const int* in_sizes, int n_in, void* d_out,
                              int out_size, void* d_ws, size_t ws_size, hipStream_t stream) {
  const float* c0 = (const float*)d_in[0];
  const float* h0 = (const float*)d_in[1];
  const float* obs = (const float*)d_in[2];
  const int* dones = (const int*)d_in[3];  // bool -> int32 per harness contract
  const float* Wp1 = (const float*)d_in[4];
  const float* bp1 = (const float*)d_in[5];
  const float* Wp2 = (const float*)d_in[6];
  const float* bp2 = (const float*)d_in[7];
  const float* Wp3 = (const float*)d_in[8];
  const float* bp3 = (const float*)d_in[9];
  const float* Wpub = (const float*)d_in[10];
  const float* bpub = (const float*)d_in[11];
  const float* Wi = (const float*)d_in[12];
  const float* Wh = (const float*)d_in[13];
  const float* b_lstm = (const float*)d_in[14];
  const float* Wv = (const float*)d_in[15];
  const float* bv = (const float*)d_in[16];
  const float* Wa = (const float*)d_in[17];
  const float* ba = (const float*)d_in[18];

  char* p = (char*)d_ws;
  auto alloc = [&](size_t bytes) -> char* {
    char* r = p;
    p += (bytes + 255) & ~(size_t)255;
    return r;
  };
  const size_t ACT_BYTES = (size_t)32768 * 512 * 2;          // 33.5 MB
  _Float16* xg = (_Float16*)alloc((size_t)32768 * 2048 * 2); // 134 MB
  _Float16* B0 = (_Float16*)alloc(ACT_BYTES);                // priv_s, then p2
  _Float16* B1 = (_Float16*)alloc(ACT_BYTES);                // publ_s, then p3
  _Float16* B2 = (_Float16*)alloc(ACT_BYTES);                // p1
  _Float16* B3 = (_Float16*)alloc(ACT_BYTES);                // px, then publ_all
  _Float16* Wp1T = (_Float16*)alloc(524288);
  _Float16* Wp2T = (_Float16*)alloc(524288);
  _Float16* Wp3T = (_Float16*)alloc(524288);
  _Float16* WpubT = (_Float16*)alloc(524288);
  _Float16* WiT = (_Float16*)alloc(2097152);
  _Float16* WhT = (_Float16*)alloc(2097152);
  _Float16* WqT = (_Float16*)alloc(32768);
  float* bperm = (float*)alloc(8192);
  float* bq = (float*)alloc(128);
  int* bar = (int*)alloc(1024);  // 8 groups x 32 ints (128B apart)
  _Float16* hb0 = (_Float16*)alloc(262144);

  _Float16* priv_s = B0;
  _Float16* p2 = B0;
  _Float16* publ_s = B1;
  _Float16* p3 = B1;
  _Float16* p1 = B2;
  _Float16* px = B3;
  _Float16* publ = B3;

  dim3 tb32(32, 8);
  transpose_cvt<<<dim3(16, 16), tb32, 0, stream>>>(Wp1, Wp1T, 512, 512, 0);
  transpose_cvt<<<dim3(16, 16), tb32, 0, stream>>>(Wp2, Wp2T, 512, 512, 0);
  transpose_cvt<<<dim3(16, 16), tb32, 0, stream>>>(Wp3, Wp3T, 512, 512, 0);
  transpose_cvt<<<dim3(16, 16), tb32, 0, stream>>>(Wpub, WpubT, 512, 512, 0);
  transpose_cvt<<<dim3(64, 16), tb32, 0, stream>>>(Wi, WiT, 512, 2048, 1);
  transpose_cvt<<<dim3(64, 16), tb32, 0, stream>>>(Wh, WhT, 512, 2048, 1);
  prep_small<<<64, 256, 0, stream>>>(Wv, bv, Wa, ba, b_lstm, WqT, bq, bperm);
  convert_obs<<<16384, 256, 0, stream>>>(obs, priv_s, publ_s);
  init_scan<<<512, 256, 0, stream>>>(h0, hb0, bar);

  // parallel GEMMs (buffer aliasing order: G1, G4, G2, G3, G5)
  // small GEMMs m-major (SW=1) for cross-XCD A reuse; big GEMM n-major.
  gemm_f16<1, 1><<<dim3(256, 4), 256, 0, stream>>>(priv_s, Wp1T, bp1, p1, 32768, 512, 512);
  gemm_f16<1, 1><<<dim3(256, 4), 256, 0, stream>>>(publ_s, WpubT, bpub, px, 32768, 512, 512);
  gemm_f16<1, 1><<<dim3(256, 4), 256, 0, stream>>>(p1, Wp2T, bp2, p2, 32768, 512, 512);
  gemm_f16<1, 1><<<dim3(256, 4), 256, 0, stream>>>(p2, Wp3T, bp3, p3, 32768, 512, 512);
  gemm_f16<0, 0><<<dim3(16, 256), 256, 0, stream>>>(px, WiT, bperm, xg, 32768, 2048, 512);

  float* outc = (float*)d_out;
  float* outh = outc + 131072;
  float* outq = outc + 262144;

  lstm_scan<<<128, 256, 0, stream>>>(WhT, xg, c0, dones, hb0, publ, outc, outh, bar);

  final_q<<<512, 256, 0, stream>>>(p3, publ, WqT, bq, outq);
}

// Round 6
// 1557.938 us; speedup vs baseline: 1.4898x; 1.4898x over previous
//
#include <hip/hip_runtime.h>
#include <hip/hip_bf16.h>
#include <hip/hip_fp16.h>
#include <cstdint>
#include <cstddef>

// ---------------------------------------------------------------------------
// Types
// ---------------------------------------------------------------------------
typedef _Float16 half8 __attribute__((ext_vector_type(8)));
typedef float float4v __attribute__((ext_vector_type(4)));
typedef unsigned int uint4v __attribute__((ext_vector_type(4)));

#define GLOBAL_AS(p) ((__attribute__((address_space(1))) void*)(p))
#define LDS_AS(p) ((__attribute__((address_space(3))) void*)(p))

// async global->LDS, 16B per lane, dest = base + lane*16 (wave-uniform base)
__device__ __forceinline__ void gll16(const void* g, void* l) {
  __builtin_amdgcn_global_load_lds(GLOBAL_AS(g), LDS_AS(l), 16, 0, 0);
}

// 16B write-through store (sc0 sc1: lands at coherence point; vmcnt ack only
// after it is globally visible) -- h exchange across blocks within the scan.
__device__ __forceinline__ void store16_cc(void* addr, uint4v v) {
  asm volatile("global_store_dwordx4 %0, %1, off sc0 sc1" ::"v"(addr), "v"(v) : "memory");
}

// issue 8 coherent 16B loads from one base (+128B strides). NO waitcnt here:
// caller issues other (overlapping) loads, then calls vm_drain().
__device__ __forceinline__ void stage8_cc_issue(const _Float16* base, uint4v& d0, uint4v& d1,
                                                uint4v& d2, uint4v& d3, uint4v& d4, uint4v& d5,
                                                uint4v& d6, uint4v& d7) {
  asm volatile(
      "global_load_dwordx4 %0, %8, off sc0 sc1\n\t"
      "global_load_dwordx4 %1, %8, off offset:128 sc0 sc1\n\t"
      "global_load_dwordx4 %2, %8, off offset:256 sc0 sc1\n\t"
      "global_load_dwordx4 %3, %8, off offset:384 sc0 sc1\n\t"
      "global_load_dwordx4 %4, %8, off offset:512 sc0 sc1\n\t"
      "global_load_dwordx4 %5, %8, off offset:640 sc0 sc1\n\t"
      "global_load_dwordx4 %6, %8, off offset:768 sc0 sc1\n\t"
      "global_load_dwordx4 %7, %8, off offset:896 sc0 sc1"
      : "=&v"(d0), "=&v"(d1), "=&v"(d2), "=&v"(d3), "=&v"(d4), "=&v"(d5), "=&v"(d6), "=&v"(d7)
      : "v"(base)
      : "memory");
}
__device__ __forceinline__ void vm_drain() {
  asm volatile("s_waitcnt vmcnt(0)" ::: "memory");
}

__device__ __forceinline__ float sigm(float x) { return 1.f / (1.f + __expf(-x)); }
__device__ __forceinline__ float tanh_fast(float x) { return 2.f / (1.f + __expf(-2.f * x)) - 1.f; }

// ---------------------------------------------------------------------------
// Weight transpose + fp32->fp16 convert.  W: K x N (row-major) -> WT: N x K.
// perm=1: output row n' = 4*(n&511) + (n>>9)   (gate interleave for Wi/Wh)
// ---------------------------------------------------------------------------
__global__ void transpose_cvt(const float* __restrict__ W, _Float16* __restrict__ WT,
                              int K, int N, int perm) {
  __shared__ float tile[32][33];
  int n0 = blockIdx.x * 32, k0 = blockIdx.y * 32;
  int tx = threadIdx.x, ty = threadIdx.y;  // (32, 8)
#pragma unroll
  for (int i = 0; i < 32; i += 8)
    tile[ty + i][tx] = W[(size_t)(k0 + ty + i) * N + n0 + tx];
  __syncthreads();
#pragma unroll
  for (int i = 0; i < 32; i += 8) {
    int n = n0 + ty + i;
    int nr = perm ? ((n & 511) * 4 + (n >> 9)) : n;
    WT[(size_t)nr * K + k0 + tx] = (_Float16)tile[tx][ty + i];
  }
}

// ---------------------------------------------------------------------------
// Build WqT (32 x 512): rows 0..20 = Wa[:,n] + Wv[:,0], rows 21..31 zero.
// bq[n] = ba[n] + bv.  bperm = gate-interleaved b_lstm.
// ---------------------------------------------------------------------------
__global__ void prep_small(const float* __restrict__ Wv, const float* __restrict__ bv,
                           const float* __restrict__ Wa, const float* __restrict__ ba,
                           const float* __restrict__ b_lstm, _Float16* __restrict__ WqT,
                           float* __restrict__ bq, float* __restrict__ bperm) {
  int idx = blockIdx.x * 256 + threadIdx.x;
  if (idx < 16384) {
    int n = idx >> 9, k = idx & 511;
    float v = (n < 21) ? (Wa[k * 21 + n] + Wv[k]) : 0.f;
    WqT[idx] = (_Float16)v;
  }
  if (idx < 2048) bperm[idx] = b_lstm[(idx & 3) * 512 + (idx >> 2)];
  if (idx < 32) bq[idx] = (idx < 21) ? (ba[idx] + bv[0]) : 0.f;
}

// ---------------------------------------------------------------------------
// obs (T*B x 1024 fp32) -> priv_s (T*B x 512 fp16), publ_s (T*B x 512 fp16)
// ---------------------------------------------------------------------------
__global__ void convert_obs(const float* __restrict__ obs, _Float16* __restrict__ priv_s,
                            _Float16* __restrict__ publ_s) {
  size_t id = (size_t)blockIdx.x * blockDim.x + threadIdx.x;  // T*B*128 threads
  size_t tb = id >> 7;
  int c8 = (int)(id & 127);
  const float4* src = (const float4*)(obs + tb * 1024 + (size_t)c8 * 8);
  float4 v0 = src[0], v1 = src[1];
  half8 h;
  h[0] = (_Float16)v0.x; h[1] = (_Float16)v0.y; h[2] = (_Float16)v0.z; h[3] = (_Float16)v0.w;
  h[4] = (_Float16)v1.x; h[5] = (_Float16)v1.y; h[6] = (_Float16)v1.z; h[7] = (_Float16)v1.w;
  _Float16* dst = (c8 < 64) ? (priv_s + tb * 512 + (size_t)c8 * 8)
                            : (publ_s + tb * 512 + (size_t)(c8 - 64) * 8);
  *(half8*)dst = h;
}

// ---------------------------------------------------------------------------
// init scan state: hb0 = h0 (fp16), unmasked (mask applied at staging time).
// Also zero barrier state.
// ---------------------------------------------------------------------------
__global__ void init_scan(const float* __restrict__ h0, _Float16* __restrict__ hbuf,
                          int* __restrict__ bar) {
  int idx = blockIdx.x * 256 + threadIdx.x;  // 131072
  hbuf[idx] = (_Float16)h0[idx];
  if (idx < 256) bar[idx] = 0;
}

// ---------------------------------------------------------------------------
// Generic fp16 GEMM: C = A(MxK) @ Bt(NxK)^T, fp32 acc, +bias [, relu] -> fp16
// 128x128 tile, 4 waves of 64x64, BK=32, global_load_lds staging.
// ---------------------------------------------------------------------------
template <int RELU>
__global__ __launch_bounds__(256) void gemm_f16(const _Float16* __restrict__ A,
                                                const _Float16* __restrict__ Bt,
                                                const float* __restrict__ bias,
                                                _Float16* __restrict__ out, int M, int N, int K) {
  __shared__ __align__(16) _Float16 Ash[4096];
  __shared__ __align__(16) _Float16 Bsh[4096];
  const int tid = threadIdx.x;
  const int w = tid >> 6, lane = tid & 63;
  const int quad = lane >> 4, fid = lane & 15;
  const int nT = blockIdx.x * 128, mT = blockIdx.y * 128;
  const int wm = (w & 1) * 64, wn = (w >> 1) * 64;
  float4v acc[4][4] = {};

  const int slot0 = (w * 2) * 64 + lane;
  const int slot1 = (w * 2 + 1) * 64 + lane;
  const int m0 = slot0 & 127, q0 = slot0 >> 7;
  const int m1 = slot1 & 127, q1 = slot1 >> 7;

  for (int k0 = 0; k0 < K; k0 += 32) {
    __syncthreads();
    gll16(A + (size_t)(mT + m0) * K + k0 + q0 * 8, &Ash[(size_t)(w * 2) * 64 * 8]);
    gll16(A + (size_t)(mT + m1) * K + k0 + q1 * 8, &Ash[(size_t)(w * 2 + 1) * 64 * 8]);
    gll16(Bt + (size_t)(nT + m0) * K + k0 + q0 * 8, &Bsh[(size_t)(w * 2) * 64 * 8]);
    gll16(Bt + (size_t)(nT + m1) * K + k0 + q1 * 8, &Bsh[(size_t)(w * 2 + 1) * 64 * 8]);
    __syncthreads();
    half8 af[4], bf[4];
#pragma unroll
    for (int i = 0; i < 4; i++)
      af[i] = *(const half8*)&Ash[(size_t)(quad * 128 + wm + i * 16 + fid) * 8];
#pragma unroll
    for (int i = 0; i < 4; i++)
      bf[i] = *(const half8*)&Bsh[(size_t)(quad * 128 + wn + i * 16 + fid) * 8];
#pragma unroll
    for (int mi = 0; mi < 4; mi++)
#pragma unroll
      for (int ni = 0; ni < 4; ni++)
        acc[mi][ni] = __builtin_amdgcn_mfma_f32_16x16x32_f16(af[mi], bf[ni], acc[mi][ni], 0, 0, 0);
  }
#pragma unroll
  for (int mi = 0; mi < 4; mi++) {
#pragma unroll
    for (int ni = 0; ni < 4; ni++) {
      int col = nT + wn + ni * 16 + fid;
      float bb = bias[col];
#pragma unroll
      for (int r = 0; r < 4; r++) {
        int row = mT + wm + mi * 16 + quad * 4 + r;
        float v = acc[mi][ni][r] + bb;
        if (RELU) v = fmaxf(v, 0.f);
        out[(size_t)row * N + col] = (_Float16)v;
      }
    }
  }
}

// ---------------------------------------------------------------------------
// Persistent LSTM scan.  1-D grid of 128 blocks, 256 threads.
// grp = bid & 7 (m-group), n-tile = bid >> 3.  Tile: 32 rows x 128 gate-cols.
// Wh and c-state register-resident.
// h exchange: small ping-pong buffers hx[2] (256x512 fp16 each, L3-hot);
// producer: epilogue -> LDS hstage -> ONE plain 16B publ store + ONE 16B
// write-through hx store per thread (tid<128).  Consumer: sc0sc1 staged loads
// (bypass L1/L2 -> read coherence point; no fences anywhere).
// xg/dones prefetch issued between staging issue and the vmcnt drain so its
// HBM latency overlaps the staging round-trip.
// Barrier: per-m-group monotonic counter, relaxed atomics only.
// ---------------------------------------------------------------------------
__global__ __launch_bounds__(256, 1) void lstm_scan(
    const _Float16* __restrict__ WhT, const _Float16* __restrict__ xg,
    const float* __restrict__ c0, const int* __restrict__ dones,
    const _Float16* __restrict__ hb0, _Float16* __restrict__ hx0,
    _Float16* __restrict__ hx1, _Float16* __restrict__ publ,
    float* __restrict__ outc, float* __restrict__ outh, int* __restrict__ bar) {
  __shared__ __align__(16) _Float16 Ash[16384];   // 32 rows x 512 k (16B slots)
  __shared__ __align__(16) _Float16 hstage[1024]; // 32 rows x 32 j

  const int tid = threadIdx.x;
  const int w = tid >> 6, lane = tid & 63;
  const int quad = lane >> 4, fid = lane & 15;
  const int bid = blockIdx.x;
  const int grp = bid & 7;          // m-group
  const int nT = (bid >> 3) * 128;  // gate-col tile
  const int jb = nT >> 2;           // j base (32 j's per block)
  const int m0 = grp * 32;          // batch-row tile
  const int wn = w * 32;            // wave's 32 gate-cols within tile
  int* cnt = bar + grp * 32;        // 128B-separated per-group counters

  const int srow = tid & 31;  // staging row
  const int scol = tid >> 5;  // 0..7

  // ---- load Wh fragments into registers (one-time) ----
  half8 bfr[16][2];
#pragma unroll
  for (int kc = 0; kc < 16; kc++)
#pragma unroll
    for (int ni = 0; ni < 2; ni++)
      bfr[kc][ni] = *(const half8*)&WhT[(size_t)(nT + wn + ni * 16 + fid) * 512 + kc * 32 + quad * 8];

  // ---- init c-state registers (lane3==0 lanes own values) ----
  const int lane3 = lane & 3;
  const int base = lane & ~3;
  float cc[2][2][4];
#pragma unroll
  for (int mi = 0; mi < 2; mi++)
#pragma unroll
    for (int ni = 0; ni < 2; ni++) {
      int col = nT + wn + ni * 16 + fid;
      int j = col >> 2;
#pragma unroll
      for (int r = 0; r < 4; r++) {
        int row = m0 + mi * 16 + quad * 4 + r;
        float cv = 0.f;
        if (lane3 == 0) cv = dones[row] ? 0.f : c0[(size_t)row * 512 + j];
        cc[mi][ni][r] = cv;
      }
    }

  for (int t = 0; t < 128; t++) {
    // ---- issue staged h loads (coherent), then xg/dones prefetch, then drain
    const _Float16* hsrc = (t == 0) ? hb0 : ((t & 1) ? hx0 : hx1);
    uint4v d0, d1, d2, d3, d4, d5, d6, d7;
    stage8_cc_issue(hsrc + (size_t)(m0 + srow) * 512 + scol * 8, d0, d1, d2, d3, d4, d5, d6, d7);

    // xg for THIS step (pinned between the two asm blocks; overlaps staging)
    _Float16 xgv[2][2][4];
#pragma unroll
    for (int mi = 0; mi < 2; mi++)
#pragma unroll
      for (int ni = 0; ni < 2; ni++) {
        int col = nT + wn + ni * 16 + fid;
#pragma unroll
        for (int r = 0; r < 4; r++)
          xgv[mi][ni][r] =
              xg[((size_t)t * 256 + m0 + mi * 16 + quad * 4 + r) * 2048 + col];
      }
    // dones for staging mask (this row) and for the t+1 c-mask
    int dstage = dones[t * 256 + m0 + srow];
    int dnv[2][4];
    {
      int tn = (t < 127) ? (t + 1) : 127;
#pragma unroll
      for (int mi = 0; mi < 2; mi++)
#pragma unroll
        for (int r = 0; r < 4; r++)
          dnv[mi][r] = dones[(size_t)tn * 256 + m0 + mi * 16 + quad * 4 + r];
    }
    vm_drain();

    if (dstage) {
      uint4v z = {0u, 0u, 0u, 0u};
      d0 = z; d1 = z; d2 = z; d3 = z; d4 = z; d5 = z; d6 = z; d7 = z;
    }
    {
      uint4v* lds = (uint4v*)Ash;
      lds[tid] = d0;
      lds[tid + 256] = d1;
      lds[tid + 512] = d2;
      lds[tid + 768] = d3;
      lds[tid + 1024] = d4;
      lds[tid + 1280] = d5;
      lds[tid + 1536] = d6;
      lds[tid + 1792] = d7;
    }
    __syncthreads();

    // ---- K-loop: 16 chunks of 32; per chunk 2 a-frags, 2x2 MFMA ----
    float4v acc[2][2] = {};
#pragma unroll
    for (int kc = 0; kc < 16; kc++) {
      half8 af[2];
#pragma unroll
      for (int mi = 0; mi < 2; mi++)
        af[mi] = *(const half8*)&Ash[(size_t)((kc * 4 + quad) * 32 + mi * 16 + fid) * 8];
#pragma unroll
      for (int mi = 0; mi < 2; mi++)
#pragma unroll
        for (int ni = 0; ni < 2; ni++)
          acc[mi][ni] = __builtin_amdgcn_mfma_f32_16x16x32_f16(af[mi], bfr[kc][ni], acc[mi][ni], 0, 0, 0);
    }

    // ---- epilogue: gates -> c,h; h into LDS hstage ----
#pragma unroll
    for (int mi = 0; mi < 2; mi++) {
#pragma unroll
      for (int ni = 0; ni < 2; ni++) {
        int jloc = w * 8 + ni * 4 + (fid >> 2);  // j - jb for this lane-quad
#pragma unroll
        for (int r = 0; r < 4; r++) {
          int lrow = mi * 16 + quad * 4 + r;
          float gate = acc[mi][ni][r] + (float)xgv[mi][ni][r];
          float gi = __shfl(gate, base + 0, 64);
          float gf = __shfl(gate, base + 1, 64);
          float gg = __shfl(gate, base + 2, 64);
          float go = __shfl(gate, base + 3, 64);
          if (lane3 == 0) {
            float i_ = sigm(gi), f_ = sigm(gf), o_ = sigm(go);
            float g_ = tanh_fast(gg);
            float c_new = f_ * cc[mi][ni][r] + i_ * g_;
            float h_new = o_ * tanh_fast(c_new);
            hstage[lrow * 32 + jloc] = (_Float16)h_new;
            if (t < 127) {
              cc[mi][ni][r] = dnv[mi][r] ? 0.f : c_new;
            } else {
              int row = m0 + lrow;
              outc[(size_t)row * 512 + jb + jloc] = c_new;
              outh[(size_t)row * 512 + jb + jloc] = h_new;
            }
          }
        }
      }
    }
    __syncthreads();

    // ---- cooperative wide stores: publ (plain) + hx (write-through) ----
    if (tid < 128) {
      int lrow = tid >> 2, seg = tid & 3;
      uint4v v = *(const uint4v*)&hstage[lrow * 32 + seg * 8];
      *(uint4v*)&publ[((size_t)t * 256 + m0 + lrow) * 512 + jb + seg * 8] = v;
      if (t < 127) {
        _Float16* hdst = (t & 1) ? hx1 : hx0;
        store16_cc(&hdst[(size_t)(m0 + lrow) * 512 + jb + seg * 8], v);
      }
    }

    // ---- per-m-group monotonic barrier (relaxed only, no fences) ----
    if (t < 127) {
      __syncthreads();  // drains wt stores (vmcnt) + hstage consumed
      if (tid == 0) {
        int target = 16 * (t + 1);
        int seen = __hip_atomic_fetch_add(cnt, 1, __ATOMIC_RELAXED, __HIP_MEMORY_SCOPE_AGENT) + 1;
        while (seen < target) {
          __builtin_amdgcn_s_sleep(1);
          seen = __hip_atomic_load(cnt, __ATOMIC_RELAXED, __HIP_MEMORY_SCOPE_AGENT);
        }
      }
      __syncthreads();
    }
  }
}

// ---------------------------------------------------------------------------
// final: q = (p3 .* publ) @ WqT^T + bq  -> out (T*B x 21) fp32
// ---------------------------------------------------------------------------
__global__ __launch_bounds__(256) void final_q(const _Float16* __restrict__ p3,
                                               const _Float16* __restrict__ publ,
                                               const _Float16* __restrict__ WqT,
                                               const float* __restrict__ bq,
                                               float* __restrict__ outq) {
  int tid = threadIdx.x, w = tid >> 6, lane = tid & 63;
  int quad = lane >> 4, fid = lane & 15;
  size_t r0 = ((size_t)blockIdx.x * 4 + w) * 16;
  float4v acc0 = {}, acc1 = {};
#pragma unroll
  for (int kk = 0; kk < 512; kk += 32) {
    half8 a = *(const half8*)(p3 + (r0 + fid) * 512 + kk + quad * 8);
    half8 b = *(const half8*)(publ + (r0 + fid) * 512 + kk + quad * 8);
    half8 af;
#pragma unroll
    for (int j = 0; j < 8; j++) af[j] = (_Float16)((float)a[j] * (float)b[j]);
    half8 b0 = *(const half8*)&WqT[(size_t)fid * 512 + kk + quad * 8];
    half8 b1 = *(const half8*)&WqT[(size_t)(16 + fid) * 512 + kk + quad * 8];
    acc0 = __builtin_amdgcn_mfma_f32_16x16x32_f16(af, b0, acc0, 0, 0, 0);
    acc1 = __builtin_amdgcn_mfma_f32_16x16x32_f16(af, b1, acc1, 0, 0, 0);
  }
#pragma unroll
  for (int r = 0; r < 4; r++) {
    size_t row = r0 + quad * 4 + r;
    int c0 = fid, c1 = 16 + fid;
    outq[row * 21 + c0] = acc0[r] + bq[c0];
    if (c1 < 21) outq[row * 21 + c1] = acc1[r] + bq[c1];
  }
}

// ---------------------------------------------------------------------------
// launcher
// ---------------------------------------------------------------------------
extern "C" void kernel_launch(void* const* d_in, const int* in_sizes, int n_in, void* d_out,
                              int out_size, void* d_ws, size_t ws_size, hipStream_t stream) {
  const float* c0 = (const float*)d_in[0];
  const float* h0 = (const float*)d_in[1];
  const float* obs = (const float*)d_in[2];
  const int* dones = (const int*)d_in[3];  // bool -> int32 per harness contract
  const float* Wp1 = (const float*)d_in[4];
  const float* bp1 = (const float*)d_in[5];
  const float* Wp2 = (const float*)d_in[6];
  const float* bp2 = (const float*)d_in[7];
  const float* Wp3 = (const float*)d_in[8];
  const float* bp3 = (const float*)d_in[9];
  const float* Wpub = (const float*)d_in[10];
  const float* bpub = (const float*)d_in[11];
  const float* Wi = (const float*)d_in[12];
  const float* Wh = (const float*)d_in[13];
  const float* b_lstm = (const float*)d_in[14];
  const float* Wv = (const float*)d_in[15];
  const float* bv = (const float*)d_in[16];
  const float* Wa = (const float*)d_in[17];
  const float* ba = (const float*)d_in[18];

  char* p = (char*)d_ws;
  auto alloc = [&](size_t bytes) -> char* {
    char* r = p;
    p += (bytes + 255) & ~(size_t)255;
    return r;
  };
  const size_t ACT_BYTES = (size_t)32768 * 512 * 2;          // 33.5 MB
  _Float16* xg = (_Float16*)alloc((size_t)32768 * 2048 * 2); // 134 MB
  _Float16* B0 = (_Float16*)alloc(ACT_BYTES);                // priv_s, then p2
  _Float16* B1 = (_Float16*)alloc(ACT_BYTES);                // publ_s, then p3
  _Float16* B2 = (_Float16*)alloc(ACT_BYTES);                // p1
  _Float16* B3 = (_Float16*)alloc(ACT_BYTES);                // px, then publ_all
  _Float16* Wp1T = (_Float16*)alloc(524288);
  _Float16* Wp2T = (_Float16*)alloc(524288);
  _Float16* Wp3T = (_Float16*)alloc(524288);
  _Float16* WpubT = (_Float16*)alloc(524288);
  _Float16* WiT = (_Float16*)alloc(2097152);
  _Float16* WhT = (_Float16*)alloc(2097152);
  _Float16* WqT = (_Float16*)alloc(32768);
  float* bperm = (float*)alloc(8192);
  float* bq = (float*)alloc(128);
  int* bar = (int*)alloc(1024);  // 8 groups x 32 ints (128B apart)
  _Float16* hb0 = (_Float16*)alloc(262144);
  _Float16* hx0 = (_Float16*)alloc(262144);
  _Float16* hx1 = (_Float16*)alloc(262144);

  _Float16* priv_s = B0;
  _Float16* p2 = B0;
  _Float16* publ_s = B1;
  _Float16* p3 = B1;
  _Float16* p1 = B2;
  _Float16* px = B3;
  _Float16* publ = B3;

  dim3 tb32(32, 8);
  transpose_cvt<<<dim3(16, 16), tb32, 0, stream>>>(Wp1, Wp1T, 512, 512, 0);
  transpose_cvt<<<dim3(16, 16), tb32, 0, stream>>>(Wp2, Wp2T, 512, 512, 0);
  transpose_cvt<<<dim3(16, 16), tb32, 0, stream>>>(Wp3, Wp3T, 512, 512, 0);
  transpose_cvt<<<dim3(16, 16), tb32, 0, stream>>>(Wpub, WpubT, 512, 512, 0);
  transpose_cvt<<<dim3(64, 16), tb32, 0, stream>>>(Wi, WiT, 512, 2048, 1);
  transpose_cvt<<<dim3(64, 16), tb32, 0, stream>>>(Wh, WhT, 512, 2048, 1);
  prep_small<<<64, 256, 0, stream>>>(Wv, bv, Wa, ba, b_lstm, WqT, bq, bperm);
  convert_obs<<<16384, 256, 0, stream>>>(obs, priv_s, publ_s);
  init_scan<<<512, 256, 0, stream>>>(h0, hb0, bar);

  // parallel GEMMs (buffer aliasing order: G1, G4, G2, G3, G5)
  gemm_f16<1><<<dim3(4, 256), 256, 0, stream>>>(priv_s, Wp1T, bp1, p1, 32768, 512, 512);
  gemm_f16<1><<<dim3(4, 256), 256, 0, stream>>>(publ_s, WpubT, bpub, px, 32768, 512, 512);
  gemm_f16<1><<<dim3(4, 256), 256, 0, stream>>>(p1, Wp2T, bp2, p2, 32768, 512, 512);
  gemm_f16<1><<<dim3(4, 256), 256, 0, stream>>>(p2, Wp3T, bp3, p3, 32768, 512, 512);
  gemm_f16<0><<<dim3(16, 256), 256, 0, stream>>>(px, WiT, bperm, xg, 32768, 2048, 512);

  float* outc = (float*)d_out;
  float* outh = outc + 131072;
  float* outq = outc + 262144;

  lstm_scan<<<128, 256, 0, stream>>>(WhT, xg, c0, dones, hb0, hx0, hx1, publ, outc, outh, bar);

  final_q<<<512, 256, 0, stream>>>(p3, publ, WqT, bq, outq);
}